// Round 3
// baseline (124.392 us; speedup 1.0000x reference)
//
#include <hip/hip_runtime.h>
#include <math.h>

// EnhancedTripletLoss, B=8192, D=256, 8 classes.
// R19: class-sorted mining with tile specialization.
//  - Rows stably sorted by label (k_hist + k_perm, deterministic ballot-rank
//    counting sort). Mining runs entirely in permuted space; k_finish maps
//    indices back through perm[] (loss is permutation-invariant).
//  - k_mine16 classifies each 64x128 tile from 4 label-range endpoints
//    (sorted => range = endpoints): ~87% pure-neg tiles run an 8-op/dot
//    epilogue (no label checks, no pos keys), ~9% pure-pos likewise, only
//    boundary tiles (~4%) run the full R18 two-sided label-checked path.
//  - Slot scheme/DPP reduce/j-side combine unchanged from R18 (proven);
//    unused sides publish neutral keys so k_finish is untouched structurally.

typedef __attribute__((ext_vector_type(8))) short short8;
typedef __attribute__((ext_vector_type(4))) float floatx4;

#define B_N 8192
#define D_K 256

__device__ __forceinline__ unsigned short f2bf_rne(float f) {
  unsigned u = __float_as_uint(f);
  u += 0x7FFFu + ((u >> 16) & 1u);
  return (unsigned short)(u >> 16);
}

// DPP helper: row_shr:N — lane i gets lane i-N within its 16-lane row; lanes
// with out-of-row source keep x (old), identity for max/min. Reduction
// accumulates into the TOP lane (l15==15).
#define DPP_SHR(x, CTRL) \
  ((unsigned)__builtin_amdgcn_update_dpp((int)(x), (int)(x), (CTRL), 0xF, 0xF, false))

// ---- counting-sort pass 1: per-256-chunk class histogram ----
__global__ void k_hist(const int* __restrict__ lab, int* __restrict__ chunkhist) {
  __shared__ int h[8];
  const int tid = threadIdx.x, b = blockIdx.x;
  if (tid < 8) h[tid] = 0;
  __syncthreads();
  atomicAdd(&h[lab[b * 256 + tid] & 7], 1);
  __syncthreads();
  if (tid < 8) chunkhist[b * 8 + tid] = h[tid];
}

// ---- counting-sort pass 2: deterministic stable scatter ----
// perm[pos] = original index; labp[pos] = label (sorted non-decreasing).
__global__ void k_perm(const int* __restrict__ lab, const int* __restrict__ chunkhist,
                       int* __restrict__ perm, int* __restrict__ labp) {
  __shared__ int ch[256];       // all 32 chunk hists
  __shared__ int base[8];       // global scatter base for this chunk, per class
  __shared__ int wcnt[4][8];    // per-wave per-class counts
  const int tid = threadIdx.x, b = blockIdx.x;
  ch[tid] = chunkhist[tid];
  __syncthreads();
  if (tid < 8) {
    const int c = tid;
    int acc = 0;
    for (int cc = 0; cc < c; ++cc)
      for (int k = 0; k < 32; ++k) acc += ch[k * 8 + cc];   // classes before c
    for (int k = 0; k < b; ++k) acc += ch[k * 8 + c];       // chunks before b
    base[c] = acc;
  }
  const int i    = b * 256 + tid;
  const int myc  = lab[i] & 7;
  const int lane = tid & 63, w = tid >> 6;
  unsigned long long bal[8];
#pragma unroll
  for (int c = 0; c < 8; ++c) bal[c] = __ballot(myc == c);
  if (lane == 0) {
#pragma unroll
    for (int c = 0; c < 8; ++c) wcnt[w][c] = (int)__popcll(bal[c]);
  }
  __syncthreads();
  int rank = (int)__popcll(bal[myc] & ((1ull << lane) - 1ull));
  for (int ww = 0; ww < w; ++ww) rank += wcnt[ww][myc];
  const int pos = base[myc] + rank;
  perm[pos] = i;
  labp[pos] = myc;
}

// ---- split to bf16 fragment-major (PERMUTED rows) + quantized row norms ----
// Tile (16 rows x 32 k) = 512 ushorts at [tile_row][tk][lane*8+j]:
// lane = quad*16 + m, row = 16*tile_row + m, k = 32*tk + quad*8 + j.
__global__ void k_split(const float* __restrict__ x, const int* __restrict__ perm,
                        unsigned short* __restrict__ xhf,
                        float* __restrict__ sqq,
                        float* __restrict__ sum, int* __restrict__ cnt,
                        int* __restrict__ done) {
  __shared__ float sw[64];
  const int tid  = threadIdx.x;
  const int lane = tid & 63;
  const int w    = tid >> 6;
  const int b    = blockIdx.x;        // tile_row
  const int m    = lane & 15;
  const int quad = lane >> 4;
  const int row  = b * 16 + m;        // permuted row
  const int rsrc = perm[row];         // original row

  float s = 0.f;
#pragma unroll
  for (int h = 0; h < 2; ++h) {
    int tk = w + h * 4;
    int kk = tk * 32 + quad * 8;
    float4 f0 = *reinterpret_cast<const float4*>(x + (size_t)rsrc * D_K + kk);
    float4 f1 = *reinterpret_cast<const float4*>(x + (size_t)rsrc * D_K + kk + 4);
    s += f0.x * f0.x + f0.y * f0.y + f0.z * f0.z + f0.w * f0.w;
    s += f1.x * f1.x + f1.y * f1.y + f1.z * f1.z + f1.w * f1.w;
    ushort4 lo, hi;
    lo.x = f2bf_rne(f0.x); lo.y = f2bf_rne(f0.y); lo.z = f2bf_rne(f0.z); lo.w = f2bf_rne(f0.w);
    hi.x = f2bf_rne(f1.x); hi.y = f2bf_rne(f1.y); hi.z = f2bf_rne(f1.z); hi.w = f2bf_rne(f1.w);
    size_t o = ((size_t)b * 8 + tk) * 512 + lane * 8;
    *reinterpret_cast<ushort4*>(xhf + o)     = lo;
    *reinterpret_cast<ushort4*>(xhf + o + 4) = hi;
  }
  s += __shfl_xor(s, 16);
  s += __shfl_xor(s, 32);
  if (quad == 0) sw[w * 16 + m] = s;
  __syncthreads();
  if (tid < 16) {
    int i = b * 16 + tid;
    float t = sw[tid] + sw[16 + tid] + sw[32 + tid] + sw[48 + tid];
    sqq[i] = fmaf(t, 128.f, 262144.f);   // pre-quantized for key calc
  }
  if (b == 0 && tid == 0) { *sum = 0.f; *cnt = 0; *done = 0; }
}

// ---- specialized mining tail: MODE 0 = pure-neg, 1 = pure-pos, 2 = mixed ----
template <int MODE>
__device__ __forceinline__ void mine_tail(
    const floatx4* acc, const int* __restrict__ labp, const float* __restrict__ sqq,
    const float* sqi, int i0, int bi, int bj, int hb, int w, int lane,
    unsigned* jbp, unsigned* jbn,
    unsigned* __restrict__ ppart, unsigned* __restrict__ npart) {
  const int wi = w >> 1, wj = w & 1;
  const int quad = lane >> 4, l15 = lane & 15;

  unsigned lip = 0;
  if (MODE == 2) {
#pragma unroll
    for (int r = 0; r < 8; ++r) {
      int ir = i0 + (r >> 2) * 16 + quad * 4 + (r & 3);
      lip |= ((unsigned)labp[ir] & 0xFu) << (r * 4);
    }
  }

  unsigned pkey[8], nkey[8];
#pragma unroll
  for (int r = 0; r < 8; ++r) { pkey[r] = 0u; nkey[r] = 0xFFFFFFFFu; }

#pragma unroll
  for (int nt = 0; nt < 4; ++nt) {
    int      j  = bj * 128 + wj * 64 + nt * 16 + l15;
    float    sj = sqq[j];
    unsigned jl = (MODE == 2) ? ((unsigned)labp[j] & 0xFu) : 0u;
    unsigned jp = 0u, jn = 0xFFFFFFFFu;
#pragma unroll
    for (int r = 0; r < 8; ++r) {
      float dot = acc[(r >> 2) * 4 + nt][r & 3];
      int   ir  = i0 + (r >> 2) * 16 + quad * 4 + (r & 3);
      unsigned keyi = ((unsigned)fmaf(-256.f, dot, sj) << 13) | (unsigned)j;
      unsigned keyj = ((unsigned)fmaf(-256.f, dot, sqi[r]) << 13) | (unsigned)ir;
      if (MODE == 2) {
        bool eq = (jl == ((lip >> (r * 4)) & 0xFu));
        unsigned pci = eq ? keyi : 0u;
        unsigned nci = eq ? 0xFFFFFFFFu : keyi;
        pkey[r] = pkey[r] > pci ? pkey[r] : pci;
        nkey[r] = nkey[r] < nci ? nkey[r] : nci;
        unsigned pcj = eq ? keyj : 0u;
        unsigned ncj = eq ? 0xFFFFFFFFu : keyj;
        jp = jp > pcj ? jp : pcj;
        jn = jn < ncj ? jn : ncj;
      } else if (MODE == 1) {
        pkey[r] = pkey[r] > keyi ? pkey[r] : keyi;
        jp = jp > keyj ? jp : keyj;
      } else {
        nkey[r] = nkey[r] < keyi ? nkey[r] : keyi;
        jn = jn < keyj ? jn : keyj;
      }
    }
    // reduce j-side across the 4 quads sharing this j, park in LDS
#pragma unroll
    for (int m = 16; m < 64; m <<= 1) {
      if (MODE != 0) {
        unsigned op = (unsigned)__shfl_xor((int)jp, m);
        jp = jp > op ? jp : op;
      }
      if (MODE != 1) {
        unsigned on = (unsigned)__shfl_xor((int)jn, m);
        jn = jn < on ? jn : on;
      }
    }
    if (quad == 0) {
      if (MODE != 0) jbp[w * 64 + nt * 16 + l15] = jp;
      if (MODE != 1) jbn[w * 64 + nt * 16 + l15] = jn;
    }
  }

  // i-side: 16-lane DPP row_shr butterfly; result lands in l15==15.
#pragma unroll
  for (int r = 0; r < 8; ++r) {
    if (MODE != 0) { unsigned tp = DPP_SHR(pkey[r], 0x118); pkey[r] = pkey[r] > tp ? pkey[r] : tp; }
    if (MODE != 1) { unsigned tn = DPP_SHR(nkey[r], 0x118); nkey[r] = nkey[r] < tn ? nkey[r] : tn; }
  }
#pragma unroll
  for (int r = 0; r < 8; ++r) {
    if (MODE != 0) { unsigned tp = DPP_SHR(pkey[r], 0x114); pkey[r] = pkey[r] > tp ? pkey[r] : tp; }
    if (MODE != 1) { unsigned tn = DPP_SHR(nkey[r], 0x114); nkey[r] = nkey[r] < tn ? nkey[r] : tn; }
  }
#pragma unroll
  for (int r = 0; r < 8; ++r) {
    if (MODE != 0) { unsigned tp = DPP_SHR(pkey[r], 0x112); pkey[r] = pkey[r] > tp ? pkey[r] : tp; }
    if (MODE != 1) { unsigned tn = DPP_SHR(nkey[r], 0x112); nkey[r] = nkey[r] < tn ? nkey[r] : tn; }
  }
#pragma unroll
  for (int r = 0; r < 8; ++r) {
    if (MODE != 0) { unsigned tp = DPP_SHR(pkey[r], 0x111); pkey[r] = pkey[r] > tp ? pkey[r] : tp; }
    if (MODE != 1) { unsigned tn = DPP_SHR(nkey[r], 0x111); nkey[r] = nkey[r] < tn ? nkey[r] : tn; }
  }
#pragma unroll
  for (int r = 0; r < 8; ++r) {
    if (l15 == 15) {
      int ir = i0 + (r >> 2) * 16 + quad * 4 + (r & 3);
      size_t idx = (size_t)(2 * bj + wj) * B_N + ir;
      ppart[idx] = (MODE == 0) ? 0u : pkey[r];
      npart[idx] = (MODE == 1) ? 0xFFFFFFFFu : nkey[r];
    }
  }

  __syncthreads();
  // j-side combine across the wi-pair sharing wj; publish slot 2*bi + hb of
  // band bj. Diagonal skipped (i-side covers the full tile there).
  if (wi == 0 && bi != bj) {
    unsigned p = 0u, n = 0xFFFFFFFFu;
    if (MODE != 0) {
      p = jbp[w * 64 + lane];
      unsigned p2 = jbp[(w + 2) * 64 + lane];
      p = p > p2 ? p : p2;
    }
    if (MODE != 1) {
      n = jbn[w * 64 + lane];
      unsigned n2 = jbn[(w + 2) * 64 + lane];
      n = n < n2 ? n : n2;
    }
    int j = bj * 128 + wj * 64 + lane;
    size_t idx = (size_t)(2 * bi + hb) * B_N + j;
    ppart[idx] = p;
    npart[idx] = n;
  }
}

// ---- MFMA Gram + two-sided mining, 4 waves/block (half-tiles), no A-LDS ----
__global__ __launch_bounds__(256, 6) void k_mine16(
    const unsigned short* __restrict__ xhf, const int* __restrict__ labp,
    const float* __restrict__ sqq,
    unsigned* __restrict__ ppart, unsigned* __restrict__ npart) {
  __shared__ unsigned jbp[4 * 64], jbn[4 * 64];  // 2 KB: per-wave j-side partials

  // decode linear block id -> (bi, bj, half); bi <= bj over 64x64 super-tiles
  int t  = blockIdx.x;
  const int hb = t & 1;               // which 64-row half of the 128-row band
  t >>= 1;
  int bi = (int)(64.5f - sqrtf(64.5f * 64.5f - 2.f * (float)t));
  int b0 = 64 * bi - (bi * (bi - 1)) / 2;
  if (t < b0) { bi--; b0 = 64 * bi - (bi * (bi - 1)) / 2; }
  else {
    int b1 = 64 * (bi + 1) - ((bi + 1) * bi) / 2;
    if (t >= b1) { bi++; b0 = b1; }
  }
  const int bj = bi + (t - b0);

  const int tid  = threadIdx.x;
  const int lane = tid & 63;
  const int w    = tid >> 6;          // 0..3
  const int wi   = w >> 1;            // 0..1 : 32-anchor band within the half
  const int wj   = w & 1;             // 0..1 : 64-j half
  const int quad = lane >> 4;
  const int i0   = bi * 128 + hb * 64 + wi * 32;

  float sqi[8];
#pragma unroll
  for (int r = 0; r < 8; ++r)
    sqi[r] = sqq[i0 + (r >> 2) * 16 + quad * 4 + (r & 3)];

  // tile classification from sorted-label range endpoints (block-uniform)
  const int la0 = labp[bi * 128 + hb * 64];
  const int la1 = labp[bi * 128 + hb * 64 + 63];
  const int lb0 = labp[bj * 128];
  const int lb1 = labp[bj * 128 + 127];

  // fragment-major offsets (ushort units): row-block rb -> rb*4096 + tk*512
  const unsigned aoff = (unsigned)(i0 >> 4) * 4096u + (unsigned)lane * 8u;
  const unsigned boff = (unsigned)(bj * 8 + wj * 4) * 4096u + (unsigned)lane * 8u;

  floatx4 acc[8];
#pragma unroll
  for (int q = 0; q < 8; ++q) acc[q] = (floatx4)0.f;

#pragma unroll
  for (int tk = 0; tk < 8; ++tk) {
    short8 Bf[4];
#pragma unroll
    for (int nt = 0; nt < 4; ++nt)
      Bf[nt] = *reinterpret_cast<const short8*>(xhf + boff + (unsigned)(nt * 4096 + tk * 512));
    short8 Af[2];
#pragma unroll
    for (int mt = 0; mt < 2; ++mt)
      Af[mt] = *reinterpret_cast<const short8*>(xhf + aoff + (unsigned)(mt * 8 + tk) * 512u);
#pragma unroll
    for (int mt = 0; mt < 2; ++mt)
#pragma unroll
      for (int nt = 0; nt < 4; ++nt)
        acc[mt * 4 + nt] = __builtin_amdgcn_mfma_f32_16x16x32_bf16(
            Af[mt], Bf[nt], acc[mt * 4 + nt], 0, 0, 0);
  }

  if (la1 < lb0 || lb1 < la0) {
    mine_tail<0>(acc, labp, sqq, sqi, i0, bi, bj, hb, w, lane, jbp, jbn, ppart, npart);
  } else if (la0 == lb1 && la1 == lb0) {   // sorted => all four labels equal
    mine_tail<1>(acc, labp, sqq, sqi, i0, bi, bj, hb, w, lane, jbp, jbn, ppart, npart);
  } else {
    mine_tail<2>(acc, labp, sqq, sqi, i0, bi, bj, hb, w, lane, jbp, jbn, ppart, npart);
  }
}

// ---- slot-reduce + exact fp32 triplet distances + loss (indices via perm) ----
__global__ void k_finish(const float* __restrict__ x, const int* __restrict__ perm,
                         const unsigned* __restrict__ ppart,
                         const unsigned* __restrict__ npart,
                         float* __restrict__ sum, int* __restrict__ cnt,
                         int* __restrict__ done, float* __restrict__ out) {
  __shared__ unsigned spk[32], snk[32];
  __shared__ float ssum[4];
  __shared__ int   scnt[4];
  const int tid = threadIdx.x;
  const int a0  = blockIdx.x * 32;

  if (tid < 32) { spk[tid] = 0u; snk[tid] = 0xFFFFFFFFu; }
  __syncthreads();

  {
    const int a    = a0 + (tid & 31);
    const int part = tid >> 5;           // 0..7 -> slots part*16 .. part*16+15
    unsigned p = 0u, n = 0xFFFFFFFFu;
#pragma unroll
    for (int s = 0; s < 16; ++s) {
      size_t idx = (size_t)(part * 16 + s) * B_N + a;
      unsigned pv = ppart[idx];
      unsigned nv = npart[idx];
      p = p > pv ? p : pv;
      n = n < nv ? n : nv;
    }
    atomicMax(&spk[tid & 31], p);        // LDS atomics: cheap, 8-way
    atomicMin(&snk[tid & 31], n);
  }
  __syncthreads();

  const int w = tid >> 6, lane = tid & 63;
  float lsum = 0.f; int lcnt = 0;
#pragma unroll
  for (int it = 0; it < 8; ++it) {
    int al = w * 8 + it;                 // 0..31
    int a  = a0 + al;                    // permuted anchor
    unsigned p = spk[al];
    unsigned n = snk[al];
    bool valid = (p != 0u) && (n != 0xFFFFFFFFu);
    int  pidx = valid ? (int)(p & 8191u) : 0;
    int  nidx = valid ? (int)(n & 8191u) : 0;
    int  ra = perm[a], rp = perm[pidx], rn = perm[nidx];

    float4 xa = *reinterpret_cast<const float4*>(x + (size_t)ra * D_K + lane * 4);
    float4 xp = *reinterpret_cast<const float4*>(x + (size_t)rp * D_K + lane * 4);
    float4 xn = *reinterpret_cast<const float4*>(x + (size_t)rn * D_K + lane * 4);
    float dx, sp = 0.f, sn = 0.f;
    dx = xa.x - xp.x + 1e-6f; sp = fmaf(dx, dx, sp);
    dx = xa.y - xp.y + 1e-6f; sp = fmaf(dx, dx, sp);
    dx = xa.z - xp.z + 1e-6f; sp = fmaf(dx, dx, sp);
    dx = xa.w - xp.w + 1e-6f; sp = fmaf(dx, dx, sp);
    dx = xa.x - xn.x + 1e-6f; sn = fmaf(dx, dx, sn);
    dx = xa.y - xn.y + 1e-6f; sn = fmaf(dx, dx, sn);
    dx = xa.z - xn.z + 1e-6f; sn = fmaf(dx, dx, sn);
    dx = xa.w - xn.w + 1e-6f; sn = fmaf(dx, dx, sn);
#pragma unroll
    for (int o = 32; o > 0; o >>= 1) {
      sp += __shfl_down(sp, o, 64);
      sn += __shfl_down(sn, o, 64);
    }
    if (lane == 0 && valid) {
      float per = sqrtf(sp) - sqrtf(sn) + 0.3f;
      if (per > 0.f) lsum += per;
      lcnt += 1;
    }
  }
  if (lane == 0) { ssum[w] = lsum; scnt[w] = lcnt; }
  __syncthreads();
  if (tid == 0) {
    atomicAdd(sum, ssum[0] + ssum[1] + ssum[2] + ssum[3]);
    atomicAdd(cnt, scnt[0] + scnt[1] + scnt[2] + scnt[3]);
    __threadfence();
    int prev = atomicAdd(done, 1);
    if (prev == gridDim.x - 1) {
      float s = atomicAdd(sum, 0.f);
      int   cc = atomicAdd(cnt, 0);
      if (cc < 1) cc = 1;
      out[0] = s / (float)cc;
    }
  }
}

extern "C" void kernel_launch(void* const* d_in, const int* in_sizes, int n_in,
                              void* d_out, int out_size, void* d_ws, size_t ws_size,
                              hipStream_t stream) {
  const float* x   = (const float*)d_in[0];
  const int*   lab = (const int*)d_in[1];
  float*       out = (float*)d_out;

  char* ws = (char*)d_ws;
  unsigned short* xhf = (unsigned short*)ws;                      // 4 MB
  int* perm      = (int*)(ws + (size_t)4096 * 1024);              // 32 KB
  int* labp      = (int*)(ws + (size_t)4096 * 1024 + 32768);      // 32 KB
  int* chunkhist = (int*)(ws + (size_t)4096 * 1024 + 65536);      // 1 KB
  float* sqq = (float*)(ws + (size_t)4608 * 1024);                // 32 KB
  char*  pb = ws + (size_t)4608 * 1024 + 65536;
  size_t seg = (size_t)128 * B_N * 4;                             // 4 MB each
  unsigned* ppart = (unsigned*)(pb);
  unsigned* npart = (unsigned*)(pb + seg);
  float* sum  = (float*)(pb + 2 * seg);
  int*   cnt  = (int*)(sum + 1);
  int*   done = (int*)(sum + 2);

  k_hist<<<32, 256, 0, stream>>>(lab, chunkhist);
  k_perm<<<32, 256, 0, stream>>>(lab, chunkhist, perm, labp);
  k_split<<<B_N / 16, 256, 0, stream>>>(x, perm, xhf, sqq, sum, cnt, done);
  k_mine16<<<4160, 256, 0, stream>>>(xhf, labp, sqq, ppart, npart);
  k_finish<<<B_N / 32, 256, 0, stream>>>(x, perm, ppart, npart, sum, cnt, done, out);
}

// Round 4
// 118.392 us; speedup vs baseline: 1.0507x; 1.0507x over previous
//
#include <hip/hip_runtime.h>
#include <math.h>

// EnhancedTripletLoss, B=8192, D=256, 8 classes.
// R20: 64x64-per-wave mining tile (data-movement round).
//  - R19 counters showed no saturated pipe (VALU 29%, MFMA 14%, HBM 16%) ->
//    bound by L1/L2 vector-load delivery: 48 KB loaded per 2048 dots (24 B/dot).
//  - Wave tile grows 32x64 -> 64x64 (mt=4,nt=4, acc=16 frags): 64 KB per 4096
//    dots = 16 B/dot, total L2 traffic 800 -> 532 MB. Grid back to triangular
//    2080 blocks of 128x128.
//  - Slot scheme: i-side slot 2*bj+wj (wi-halves write disjoint rows);
//    j-side combines wi-pairs, publishes value to slot 2*bi+wj and NEUTRAL to
//    slot 2*bi+(1-wj) at its 64 j's (other half symmetric); diagonal: i-side
//    covers both slots, j-side skipped. 128 slots/anchor, each written once.
//  - Class-sort + MODE specialization retained from R19 (proven).

typedef __attribute__((ext_vector_type(8))) short short8;
typedef __attribute__((ext_vector_type(4))) float floatx4;

#define B_N 8192
#define D_K 256

__device__ __forceinline__ unsigned short f2bf_rne(float f) {
  unsigned u = __float_as_uint(f);
  u += 0x7FFFu + ((u >> 16) & 1u);
  return (unsigned short)(u >> 16);
}

// DPP helper: row_shr:N — lane i gets lane i-N within its 16-lane row; lanes
// with out-of-row source keep x (old), identity for max/min. Reduction
// accumulates into the TOP lane (l15==15).
#define DPP_SHR(x, CTRL) \
  ((unsigned)__builtin_amdgcn_update_dpp((int)(x), (int)(x), (CTRL), 0xF, 0xF, false))

// ---- counting-sort pass 1: per-256-chunk class histogram ----
__global__ void k_hist(const int* __restrict__ lab, int* __restrict__ chunkhist) {
  __shared__ int h[8];
  const int tid = threadIdx.x, b = blockIdx.x;
  if (tid < 8) h[tid] = 0;
  __syncthreads();
  atomicAdd(&h[lab[b * 256 + tid] & 7], 1);
  __syncthreads();
  if (tid < 8) chunkhist[b * 8 + tid] = h[tid];
}

// ---- counting-sort pass 2: deterministic stable scatter ----
// perm[pos] = original index; labp[pos] = label (sorted non-decreasing).
__global__ void k_perm(const int* __restrict__ lab, const int* __restrict__ chunkhist,
                       int* __restrict__ perm, int* __restrict__ labp) {
  __shared__ int ch[256];       // all 32 chunk hists
  __shared__ int base[8];       // global scatter base for this chunk, per class
  __shared__ int wcnt[4][8];    // per-wave per-class counts
  const int tid = threadIdx.x, b = blockIdx.x;
  ch[tid] = chunkhist[tid];
  __syncthreads();
  if (tid < 8) {
    const int c = tid;
    int acc = 0;
    for (int cc = 0; cc < c; ++cc)
      for (int k = 0; k < 32; ++k) acc += ch[k * 8 + cc];   // classes before c
    for (int k = 0; k < b; ++k) acc += ch[k * 8 + c];       // chunks before b
    base[c] = acc;
  }
  const int i    = b * 256 + tid;
  const int myc  = lab[i] & 7;
  const int lane = tid & 63, w = tid >> 6;
  unsigned long long bal[8];
#pragma unroll
  for (int c = 0; c < 8; ++c) bal[c] = __ballot(myc == c);
  if (lane == 0) {
#pragma unroll
    for (int c = 0; c < 8; ++c) wcnt[w][c] = (int)__popcll(bal[c]);
  }
  __syncthreads();
  int rank = (int)__popcll(bal[myc] & ((1ull << lane) - 1ull));
  for (int ww = 0; ww < w; ++ww) rank += wcnt[ww][myc];
  const int pos = base[myc] + rank;
  perm[pos] = i;
  labp[pos] = myc;
}

// ---- split to bf16 fragment-major (PERMUTED rows) + quantized row norms ----
// Tile (16 rows x 32 k) = 512 ushorts at [tile_row][tk][lane*8+j]:
// lane = quad*16 + m, row = 16*tile_row + m, k = 32*tk + quad*8 + j.
__global__ void k_split(const float* __restrict__ x, const int* __restrict__ perm,
                        unsigned short* __restrict__ xhf,
                        float* __restrict__ sqq,
                        float* __restrict__ sum, int* __restrict__ cnt,
                        int* __restrict__ done) {
  __shared__ float sw[64];
  const int tid  = threadIdx.x;
  const int lane = tid & 63;
  const int w    = tid >> 6;
  const int b    = blockIdx.x;        // tile_row
  const int m    = lane & 15;
  const int quad = lane >> 4;
  const int row  = b * 16 + m;        // permuted row
  const int rsrc = perm[row];         // original row

  float s = 0.f;
#pragma unroll
  for (int h = 0; h < 2; ++h) {
    int tk = w + h * 4;
    int kk = tk * 32 + quad * 8;
    float4 f0 = *reinterpret_cast<const float4*>(x + (size_t)rsrc * D_K + kk);
    float4 f1 = *reinterpret_cast<const float4*>(x + (size_t)rsrc * D_K + kk + 4);
    s += f0.x * f0.x + f0.y * f0.y + f0.z * f0.z + f0.w * f0.w;
    s += f1.x * f1.x + f1.y * f1.y + f1.z * f1.z + f1.w * f1.w;
    ushort4 lo, hi;
    lo.x = f2bf_rne(f0.x); lo.y = f2bf_rne(f0.y); lo.z = f2bf_rne(f0.z); lo.w = f2bf_rne(f0.w);
    hi.x = f2bf_rne(f1.x); hi.y = f2bf_rne(f1.y); hi.z = f2bf_rne(f1.z); hi.w = f2bf_rne(f1.w);
    size_t o = ((size_t)b * 8 + tk) * 512 + lane * 8;
    *reinterpret_cast<ushort4*>(xhf + o)     = lo;
    *reinterpret_cast<ushort4*>(xhf + o + 4) = hi;
  }
  s += __shfl_xor(s, 16);
  s += __shfl_xor(s, 32);
  if (quad == 0) sw[w * 16 + m] = s;
  __syncthreads();
  if (tid < 16) {
    int i = b * 16 + tid;
    float t = sw[tid] + sw[16 + tid] + sw[32 + tid] + sw[48 + tid];
    sqq[i] = fmaf(t, 128.f, 262144.f);   // pre-quantized for key calc
  }
  if (b == 0 && tid == 0) { *sum = 0.f; *cnt = 0; *done = 0; }
}

// ---- specialized mining tail: MODE 0 = pure-neg, 1 = pure-pos, 2 = mixed ----
// 16 rows/lane-group now (mt=4): r = mt*4+reg -> ir = i0 + mt*16 + quad*4 + reg.
template <int MODE>
__device__ __forceinline__ void mine_tail(
    const floatx4* acc, const int* __restrict__ labp, const float* __restrict__ sqq,
    int i0, int bi, int bj, int w, int lane,
    unsigned* jbp, unsigned* jbn,
    unsigned* __restrict__ ppart, unsigned* __restrict__ npart) {
  const int wj = w & 1;
  const int quad = lane >> 4, l15 = lane & 15;

  float sqi[16];
#pragma unroll
  for (int r = 0; r < 16; ++r)
    sqi[r] = sqq[i0 + (r >> 2) * 16 + quad * 4 + (r & 3)];

  unsigned long long lip = 0ull;
  if (MODE == 2) {
#pragma unroll
    for (int r = 0; r < 16; ++r) {
      int ir = i0 + (r >> 2) * 16 + quad * 4 + (r & 3);
      lip |= (unsigned long long)((unsigned)labp[ir] & 0xFu) << (r * 4);
    }
  }

  unsigned pkey[16], nkey[16];
#pragma unroll
  for (int r = 0; r < 16; ++r) { pkey[r] = 0u; nkey[r] = 0xFFFFFFFFu; }

#pragma unroll
  for (int nt = 0; nt < 4; ++nt) {
    const int      j  = bj * 128 + wj * 64 + nt * 16 + l15;
    const float    sj = sqq[j];
    const unsigned jl = (MODE == 2) ? ((unsigned)labp[j] & 0xFu) : 0u;
    unsigned jp = 0u, jn = 0xFFFFFFFFu;
#pragma unroll
    for (int r = 0; r < 16; ++r) {
      float dot = acc[(r >> 2) * 4 + nt][r & 3];
      int   ir  = i0 + (r >> 2) * 16 + quad * 4 + (r & 3);
      unsigned keyi = ((unsigned)fmaf(-256.f, dot, sj) << 13) | (unsigned)j;
      unsigned keyj = ((unsigned)fmaf(-256.f, dot, sqi[r]) << 13) | (unsigned)ir;
      if (MODE == 2) {
        bool eq = (jl == (unsigned)((lip >> (r * 4)) & 0xFull));
        unsigned pci = eq ? keyi : 0u;
        unsigned nci = eq ? 0xFFFFFFFFu : keyi;
        pkey[r] = pkey[r] > pci ? pkey[r] : pci;
        nkey[r] = nkey[r] < nci ? nkey[r] : nci;
        unsigned pcj = eq ? keyj : 0u;
        unsigned ncj = eq ? 0xFFFFFFFFu : keyj;
        jp = jp > pcj ? jp : pcj;
        jn = jn < ncj ? jn : ncj;
      } else if (MODE == 1) {
        pkey[r] = pkey[r] > keyi ? pkey[r] : keyi;
        jp = jp > keyj ? jp : keyj;
      } else {
        nkey[r] = nkey[r] < keyi ? nkey[r] : keyi;
        jn = jn < keyj ? jn : keyj;
      }
    }
    // reduce j-side across the 4 quads sharing this j, park in LDS
#pragma unroll
    for (int m = 16; m < 64; m <<= 1) {
      if (MODE != 0) { unsigned op = (unsigned)__shfl_xor((int)jp, m); jp = jp > op ? jp : op; }
      if (MODE != 1) { unsigned on = (unsigned)__shfl_xor((int)jn, m); jn = jn < on ? jn : on; }
    }
    if (quad == 0) {
      if (MODE != 0) jbp[w * 64 + nt * 16 + l15] = jp;
      if (MODE != 1) jbn[w * 64 + nt * 16 + l15] = jn;
    }
  }

  // i-side: 16-lane DPP row_shr butterfly; result lands in l15==15.
#pragma unroll
  for (int r = 0; r < 16; ++r) {
    if (MODE != 0) { unsigned tp = DPP_SHR(pkey[r], 0x118); pkey[r] = pkey[r] > tp ? pkey[r] : tp; }
    if (MODE != 1) { unsigned tn = DPP_SHR(nkey[r], 0x118); nkey[r] = nkey[r] < tn ? nkey[r] : tn; }
  }
#pragma unroll
  for (int r = 0; r < 16; ++r) {
    if (MODE != 0) { unsigned tp = DPP_SHR(pkey[r], 0x114); pkey[r] = pkey[r] > tp ? pkey[r] : tp; }
    if (MODE != 1) { unsigned tn = DPP_SHR(nkey[r], 0x114); nkey[r] = nkey[r] < tn ? nkey[r] : tn; }
  }
#pragma unroll
  for (int r = 0; r < 16; ++r) {
    if (MODE != 0) { unsigned tp = DPP_SHR(pkey[r], 0x112); pkey[r] = pkey[r] > tp ? pkey[r] : tp; }
    if (MODE != 1) { unsigned tn = DPP_SHR(nkey[r], 0x112); nkey[r] = nkey[r] < tn ? nkey[r] : tn; }
  }
#pragma unroll
  for (int r = 0; r < 16; ++r) {
    if (MODE != 0) { unsigned tp = DPP_SHR(pkey[r], 0x111); pkey[r] = pkey[r] > tp ? pkey[r] : tp; }
    if (MODE != 1) { unsigned tn = DPP_SHR(nkey[r], 0x111); nkey[r] = nkey[r] < tn ? nkey[r] : tn; }
  }
#pragma unroll
  for (int r = 0; r < 16; ++r) {
    if (l15 == 15) {
      int ir = i0 + (r >> 2) * 16 + quad * 4 + (r & 3);
      size_t idx = (size_t)(2 * bj + wj) * B_N + ir;
      ppart[idx] = (MODE == 0) ? 0u : pkey[r];
      npart[idx] = (MODE == 1) ? 0xFFFFFFFFu : nkey[r];
    }
  }

  __syncthreads();
  // j-side combine across the wi-pair sharing wj (w in {0,1} with w+2).
  // Publish value to slot 2*bi+wj and NEUTRAL to slot 2*bi+(1-wj) at these
  // 64 j's; the other wj pair covers the other half symmetrically.
  // Diagonal skipped (i-side wrote slots 2*bi+{0,1} for the whole band).
  if ((w >> 1) == 0 && bi != bj) {
    unsigned p = 0u, n = 0xFFFFFFFFu;
    if (MODE != 0) {
      p = jbp[w * 64 + lane];
      unsigned p2 = jbp[(w + 2) * 64 + lane];
      p = p > p2 ? p : p2;
    }
    if (MODE != 1) {
      n = jbn[w * 64 + lane];
      unsigned n2 = jbn[(w + 2) * 64 + lane];
      n = n < n2 ? n : n2;
    }
    int j = bj * 128 + wj * 64 + lane;
    size_t v = (size_t)(2 * bi + wj)       * B_N + j;
    size_t u = (size_t)(2 * bi + (1 - wj)) * B_N + j;
    ppart[v] = p;   npart[v] = n;
    ppart[u] = 0u;  npart[u] = 0xFFFFFFFFu;
  }
}

// ---- MFMA Gram + two-sided mining, 4 waves/block, 64x64 per wave ----
__global__ __launch_bounds__(256, 3) void k_mine16(
    const unsigned short* __restrict__ xhf, const int* __restrict__ labp,
    const float* __restrict__ sqq,
    unsigned* __restrict__ ppart, unsigned* __restrict__ npart) {
  __shared__ unsigned jbp[4 * 64], jbn[4 * 64];  // 2 KB: per-wave j-side partials

  // decode linear block id -> (bi, bj), bi <= bj, over 64x64 block grid
  int t  = blockIdx.x;
  int bi = (int)(64.5f - sqrtf(64.5f * 64.5f - 2.f * (float)t));
  int b0 = 64 * bi - (bi * (bi - 1)) / 2;
  if (t < b0) { bi--; b0 = 64 * bi - (bi * (bi - 1)) / 2; }
  else {
    int b1 = 64 * (bi + 1) - ((bi + 1) * bi) / 2;
    if (t >= b1) { bi++; b0 = b1; }
  }
  const int bj = bi + (t - b0);

  const int tid  = threadIdx.x;
  const int lane = tid & 63;
  const int w    = tid >> 6;          // 0..3
  const int wi   = w >> 1;            // 0..1 : 64-row half of the band
  const int wj   = w & 1;             // 0..1 : 64-col half
  const int i0   = bi * 128 + wi * 64;

  // tile classification from sorted-label range endpoints (block-uniform)
  const int la0 = labp[bi * 128];
  const int la1 = labp[bi * 128 + 127];
  const int lb0 = labp[bj * 128];
  const int lb1 = labp[bj * 128 + 127];

  // fragment-major offsets (ushort units): row-block rb -> rb*4096 + tk*512
  const unsigned aoff = (unsigned)(bi * 8 + wi * 4) * 4096u + (unsigned)lane * 8u;
  const unsigned boff = (unsigned)(bj * 8 + wj * 4) * 4096u + (unsigned)lane * 8u;

  floatx4 acc[16];
#pragma unroll
  for (int q = 0; q < 16; ++q) acc[q] = (floatx4)0.f;

#pragma unroll
  for (int tk = 0; tk < 8; ++tk) {
    short8 Bf[4];
#pragma unroll
    for (int nt = 0; nt < 4; ++nt)
      Bf[nt] = *reinterpret_cast<const short8*>(xhf + boff + (unsigned)(nt * 4096 + tk * 512));
    short8 Af[4];
#pragma unroll
    for (int mt = 0; mt < 4; ++mt)
      Af[mt] = *reinterpret_cast<const short8*>(xhf + aoff + (unsigned)(mt * 4096 + tk * 512));
#pragma unroll
    for (int mt = 0; mt < 4; ++mt)
#pragma unroll
      for (int nt = 0; nt < 4; ++nt)
        acc[mt * 4 + nt] = __builtin_amdgcn_mfma_f32_16x16x32_bf16(
            Af[mt], Bf[nt], acc[mt * 4 + nt], 0, 0, 0);
  }

  if (la1 < lb0 || lb1 < la0) {
    mine_tail<0>(acc, labp, sqq, i0, bi, bj, w, lane, jbp, jbn, ppart, npart);
  } else if (la0 == lb1 && la1 == lb0) {   // sorted => all four labels equal
    mine_tail<1>(acc, labp, sqq, i0, bi, bj, w, lane, jbp, jbn, ppart, npart);
  } else {
    mine_tail<2>(acc, labp, sqq, i0, bi, bj, w, lane, jbp, jbn, ppart, npart);
  }
}

// ---- slot-reduce + exact fp32 triplet distances + loss (indices via perm) ----
__global__ void k_finish(const float* __restrict__ x, const int* __restrict__ perm,
                         const unsigned* __restrict__ ppart,
                         const unsigned* __restrict__ npart,
                         float* __restrict__ sum, int* __restrict__ cnt,
                         int* __restrict__ done, float* __restrict__ out) {
  __shared__ unsigned spk[32], snk[32];
  __shared__ float ssum[4];
  __shared__ int   scnt[4];
  const int tid = threadIdx.x;
  const int a0  = blockIdx.x * 32;

  if (tid < 32) { spk[tid] = 0u; snk[tid] = 0xFFFFFFFFu; }
  __syncthreads();

  {
    const int a    = a0 + (tid & 31);
    const int part = tid >> 5;           // 0..7 -> slots part*16 .. part*16+15
    unsigned p = 0u, n = 0xFFFFFFFFu;
#pragma unroll
    for (int s = 0; s < 16; ++s) {
      size_t idx = (size_t)(part * 16 + s) * B_N + a;
      unsigned pv = ppart[idx];
      unsigned nv = npart[idx];
      p = p > pv ? p : pv;
      n = n < nv ? n : nv;
    }
    atomicMax(&spk[tid & 31], p);        // LDS atomics: cheap, 8-way
    atomicMin(&snk[tid & 31], n);
  }
  __syncthreads();

  const int w = tid >> 6, lane = tid & 63;
  float lsum = 0.f; int lcnt = 0;
#pragma unroll
  for (int it = 0; it < 8; ++it) {
    int al = w * 8 + it;                 // 0..31
    int a  = a0 + al;                    // permuted anchor
    unsigned p = spk[al];
    unsigned n = snk[al];
    bool valid = (p != 0u) && (n != 0xFFFFFFFFu);
    int  pidx = valid ? (int)(p & 8191u) : 0;
    int  nidx = valid ? (int)(n & 8191u) : 0;
    int  ra = perm[a], rp = perm[pidx], rn = perm[nidx];

    float4 xa = *reinterpret_cast<const float4*>(x + (size_t)ra * D_K + lane * 4);
    float4 xp = *reinterpret_cast<const float4*>(x + (size_t)rp * D_K + lane * 4);
    float4 xn = *reinterpret_cast<const float4*>(x + (size_t)rn * D_K + lane * 4);
    float dx, sp = 0.f, sn = 0.f;
    dx = xa.x - xp.x + 1e-6f; sp = fmaf(dx, dx, sp);
    dx = xa.y - xp.y + 1e-6f; sp = fmaf(dx, dx, sp);
    dx = xa.z - xp.z + 1e-6f; sp = fmaf(dx, dx, sp);
    dx = xa.w - xp.w + 1e-6f; sp = fmaf(dx, dx, sp);
    dx = xa.x - xn.x + 1e-6f; sn = fmaf(dx, dx, sn);
    dx = xa.y - xn.y + 1e-6f; sn = fmaf(dx, dx, sn);
    dx = xa.z - xn.z + 1e-6f; sn = fmaf(dx, dx, sn);
    dx = xa.w - xn.w + 1e-6f; sn = fmaf(dx, dx, sn);
#pragma unroll
    for (int o = 32; o > 0; o >>= 1) {
      sp += __shfl_down(sp, o, 64);
      sn += __shfl_down(sn, o, 64);
    }
    if (lane == 0 && valid) {
      float per = sqrtf(sp) - sqrtf(sn) + 0.3f;
      if (per > 0.f) lsum += per;
      lcnt += 1;
    }
  }
  if (lane == 0) { ssum[w] = lsum; scnt[w] = lcnt; }
  __syncthreads();
  if (tid == 0) {
    atomicAdd(sum, ssum[0] + ssum[1] + ssum[2] + ssum[3]);
    atomicAdd(cnt, scnt[0] + scnt[1] + scnt[2] + scnt[3]);
    __threadfence();
    int prev = atomicAdd(done, 1);
    if (prev == gridDim.x - 1) {
      float s = atomicAdd(sum, 0.f);
      int   cc = atomicAdd(cnt, 0);
      if (cc < 1) cc = 1;
      out[0] = s / (float)cc;
    }
  }
}

extern "C" void kernel_launch(void* const* d_in, const int* in_sizes, int n_in,
                              void* d_out, int out_size, void* d_ws, size_t ws_size,
                              hipStream_t stream) {
  const float* x   = (const float*)d_in[0];
  const int*   lab = (const int*)d_in[1];
  float*       out = (float*)d_out;

  char* ws = (char*)d_ws;
  unsigned short* xhf = (unsigned short*)ws;                      // 4 MB
  int* perm      = (int*)(ws + (size_t)4096 * 1024);              // 32 KB
  int* labp      = (int*)(ws + (size_t)4096 * 1024 + 32768);      // 32 KB
  int* chunkhist = (int*)(ws + (size_t)4096 * 1024 + 65536);      // 1 KB
  float* sqq = (float*)(ws + (size_t)4608 * 1024);                // 32 KB
  char*  pb = ws + (size_t)4608 * 1024 + 65536;
  size_t seg = (size_t)128 * B_N * 4;                             // 4 MB each
  unsigned* ppart = (unsigned*)(pb);
  unsigned* npart = (unsigned*)(pb + seg);
  float* sum  = (float*)(pb + 2 * seg);
  int*   cnt  = (int*)(sum + 1);
  int*   done = (int*)(sum + 2);

  k_hist<<<32, 256, 0, stream>>>(lab, chunkhist);
  k_perm<<<32, 256, 0, stream>>>(lab, chunkhist, perm, labp);
  k_split<<<B_N / 16, 256, 0, stream>>>(x, perm, xhf, sqq, sum, cnt, done);
  k_mine16<<<2080, 256, 0, stream>>>(xhf, labp, sqq, ppart, npart);
  k_finish<<<B_N / 32, 256, 0, stream>>>(x, perm, ppart, npart, sum, cnt, done, out);
}